// Round 8
// baseline (945.850 us; speedup 1.0000x reference)
//
#include <hip/hip_runtime.h>
#include <hip/hip_bf16.h>
#include <stdint.h>

#define T_TOK 8192
#define H_DIM 2048
#define I_DIM 1408
#define E_NUM 8
#define GU2   2816   // 2*I

typedef __attribute__((ext_vector_type(8))) short bf16x8;
typedef __attribute__((ext_vector_type(4))) float f32x4;

__device__ __forceinline__ void async_copy16(const void* g, void* lds) {
  __builtin_amdgcn_global_load_lds(
      (const __attribute__((address_space(1))) uint32_t*)g,
      (__attribute__((address_space(3))) uint32_t*)lds, 16, 0, 0);
}

#define PHASE_BAR() __builtin_amdgcn_s_barrier()
#define WAIT_VM(n)  asm volatile("s_waitcnt vmcnt(" #n ")")

// Fragment read: all swizzle math hoisted to per-lane constants; each read is
// base + compile-time offset -> ds_read_b128 with immediate, zero per-read VALU.
#define RD(arr, off) (*(const bf16x8*)&(arr)[(off)])

__device__ __forceinline__ float bfu2f(unsigned short u) {
  union { unsigned int i; float f; } v; v.i = ((unsigned int)u) << 16; return v.f;
}

// ---------------- f32 -> bf16 conversion (weights) ----------------
__global__ __launch_bounds__(256) void cvt_kernel(const float4* __restrict__ in,
                                                  ushort4* __restrict__ out, int n4) {
  int i = blockIdx.x * blockDim.x + threadIdx.x;
  int stride = gridDim.x * blockDim.x;
  for (; i < n4; i += stride) {
    float4 v = in[i];
    ushort4 o;
    __hip_bfloat16 b;
    b = __float2bfloat16(v.x); o.x = *reinterpret_cast<unsigned short*>(&b);
    b = __float2bfloat16(v.y); o.y = *reinterpret_cast<unsigned short*>(&b);
    b = __float2bfloat16(v.z); o.z = *reinterpret_cast<unsigned short*>(&b);
    b = __float2bfloat16(v.w); o.w = *reinterpret_cast<unsigned short*>(&b);
    out[i] = o;
  }
}

// ---------- gating: logits -> top2 -> lists + inverse; also writes xb ----------
__global__ __launch_bounds__(256) void gating_kernel(
    const float* __restrict__ x, const float* __restrict__ gw,
    int* __restrict__ cnt, int* __restrict__ idx, float* __restrict__ wgt,
    int* __restrict__ invE, int* __restrict__ invP,
    __hip_bfloat16* __restrict__ xb) {
  int wave = threadIdx.x >> 6, lane = threadIdx.x & 63;
  int t = blockIdx.x * 4 + wave;
  if (t >= T_TOK) return;
  const float4* xr = (const float4*)(x + (size_t)t * H_DIM);
  ushort4* xo = (ushort4*)((unsigned short*)xb + (size_t)t * H_DIM);
  float acc[E_NUM];
#pragma unroll
  for (int e = 0; e < E_NUM; ++e) acc[e] = 0.f;
#pragma unroll
  for (int i = 0; i < H_DIM / 256; ++i) {
    int c = i * 64 + lane;
    float4 xv = xr[c];
    ushort4 o;
    __hip_bfloat16 b;
    b = __float2bfloat16(xv.x); o.x = *reinterpret_cast<unsigned short*>(&b);
    b = __float2bfloat16(xv.y); o.y = *reinterpret_cast<unsigned short*>(&b);
    b = __float2bfloat16(xv.z); o.z = *reinterpret_cast<unsigned short*>(&b);
    b = __float2bfloat16(xv.w); o.w = *reinterpret_cast<unsigned short*>(&b);
    xo[c] = o;
#pragma unroll
    for (int e = 0; e < E_NUM; ++e) {
      float4 g = ((const float4*)(gw + (size_t)e * H_DIM))[c];
      acc[e] += xv.x * g.x + xv.y * g.y + xv.z * g.z + xv.w * g.w;
    }
  }
#pragma unroll
  for (int e = 0; e < E_NUM; ++e) {
    float s = acc[e];
#pragma unroll
    for (int o = 32; o > 0; o >>= 1) s += __shfl_xor(s, o);
    acc[e] = s;
  }
  if (lane == 0) {
    int i1 = 0; float v1 = acc[0];
#pragma unroll
    for (int e = 1; e < E_NUM; ++e) if (acc[e] > v1) { v1 = acc[e]; i1 = e; }
    int i2 = -1; float v2 = -3.4e38f;
#pragma unroll
    for (int e = 0; e < E_NUM; ++e) if (e != i1 && acc[e] > v2) { v2 = acc[e]; i2 = e; }
    float p2 = expf(v2 - v1);
    float winv = 1.f / (1.f + p2);
    float w1 = winv, w2 = p2 * winv;
    int p = atomicAdd(&cnt[i1], 1);
    idx[i1 * T_TOK + p] = t; wgt[i1 * T_TOK + p] = w1;
    invE[2 * t] = i1; invP[2 * t] = p;
    p = atomicAdd(&cnt[i2], 1);
    idx[i2 * T_TOK + p] = t; wgt[i2 * T_TOK + p] = w2;
    invE[2 * t + 1] = i2; invP[2 * t + 1] = p;
  }
}

__global__ void prefix_kernel(const int* __restrict__ cnt, int* __restrict__ base) {
  if (threadIdx.x == 0 && blockIdx.x == 0) {
    int s = 0;
#pragma unroll
    for (int e = 0; e < E_NUM; ++e) { base[e] = s; s += cnt[e]; }
  }
}

// ============================================================================
// GEMM1: 256 slot-rows x 128 h-cols. r5 schedule + (a) per-lane precomputed
// swizzled LDS offsets (zero per-read VALU), (b) next-phase reads issued inside
// the MFMA region (LDS pipe overlaps matrix pipe), (c) trimmed grid.
// ============================================================================
__global__ __launch_bounds__(512, 2) void gemm1_kernel(
    const __hip_bfloat16* __restrict__ xb, const __hip_bfloat16* __restrict__ wb1,
    const int* __restrict__ cnt, const int* __restrict__ base, const int* __restrict__ idx,
    __hip_bfloat16* __restrict__ hbuf)
{
  // 880 blocks = 8 XCDs x 110 (10 row-blocks x 11 col-blocks per expert)
  int lin = blockIdx.x;
  int swz = (lin & 7) * 110 + (lin >> 3);
  int e = swz / 110; int rem = swz - e * 110;
  int by = rem / 11; int bx = rem - by * 11;
  const int ne = cnt[e];
  const int rowbase = by * 256;
  if (rowbase >= ne) return;
  const int jbase = bx * 128;
  const int hb = base[e];

  __shared__ short sA[2][256 * 64];
  __shared__ short sB[2][256 * 64];

  const int tid = threadIdx.x, wid = tid >> 6, lane = tid & 63;
  const int wr = wid >> 2, wc = wid & 3;
  const int l15 = lane & 15, lhi = lane >> 4;
  const int* idx_e = idx + e * T_TOK;
  const char* xs = (const char*)xb;
  const char* w1s = (const char*)wb1 + (size_t)e * GU2 * H_DIM * 2;

  // Per-lane LDS read constants (shorts): byte = row*128 + kcol*2 ^ (row&7)<<4
  // decomposes (row&7 == l15&7 for all fragment rows) into:
  const int swz45 = (lhi ^ (l15 & 3)) << 3;          // swizzled bits 4-5
  const int b6s   = ((l15 >> 2) & 1) << 5;           // bit 6 of xor mask
  const int kOff0 = swz45 + (0 ^ b6s);
  const int kOff1 = swz45 + (32 ^ b6s);
  const int aRow  = (wr * 128 + l15) * 64;           // A fragment row base
  const int bRow  = (wc * 64 + l15) * 64;            // B fragment row base

  const int cb = ((lane & 7) ^ (lane >> 3)) << 4;    // pre-swizzled source col
  const char* aSrc[4]; const char* bSrc[4];
#pragma unroll
  for (int q = 0; q < 4; ++q) {
    int r = q * 64 + wid * 8 + (lane >> 3);
    int i = rowbase + r; if (i > ne - 1) i = ne - 1;
    aSrc[q] = xs + (size_t)idx_e[i] * (H_DIM * 2) + cb;
    int s = r & 63;
    int wrow = (s < 32) ? (jbase + q * 32 + s) : (I_DIM + jbase + q * 32 + (s - 32));
    bSrc[q] = w1s + (size_t)wrow * (H_DIM * 2) + cb;
  }

  const int NK = H_DIM / 64;  // 32 (even)

  // prologue: B(0), A(0), B(1), A(1); drain tile-0's 8, keep tile-1's 8
#pragma unroll
  for (int q = 0; q < 4; ++q) async_copy16(bSrc[q], &sB[0][q * 4096 + wid * 512]);
#pragma unroll
  for (int q = 0; q < 4; ++q) async_copy16(aSrc[q], &sA[0][q * 4096 + wid * 512]);
#pragma unroll
  for (int q = 0; q < 4; ++q) async_copy16(bSrc[q] + 128, &sB[1][q * 4096 + wid * 512]);
#pragma unroll
  for (int q = 0; q < 4; ++q) async_copy16(aSrc[q] + 128, &sA[1][q * 4096 + wid * 512]);
  WAIT_VM(8);
  PHASE_BAR();

  f32x4 acc[8][4];
#pragma unroll
  for (int m = 0; m < 8; ++m)
#pragma unroll
    for (int n = 0; n < 4; ++n) acc[m][n] = (f32x4){0, 0, 0, 0};

  auto iter = [&](const int BUF, const int ALT, const int t) {
    const bool stA = (t >= 1) && (t + 1 < NK);
    const bool stB = (t + 2 < NK);
    const size_t kA = (size_t)(t + 1) * 128;
    const size_t kB = (size_t)(t + 2) * 128;
    bf16x8 aLo[4][2], aHi[4][2], bg[2][2], bu[2][2];

    // ---- ph1: stage A-lo(t+1); reads aLo+bg (+bu for ph2) inside MFMA region ----
    if (stA) {
      async_copy16(aSrc[0] + kA, &sA[ALT][0 * 4096 + wid * 512]);
      async_copy16(aSrc[1] + kA, &sA[ALT][1 * 4096 + wid * 512]);
    }
    PHASE_BAR();
#pragma unroll
    for (int m = 0; m < 4; ++m) {
      aLo[m][0] = RD(sA[BUF], aRow + m * 1024 + kOff0);
      aLo[m][1] = RD(sA[BUF], aRow + m * 1024 + kOff1);
    }
#pragma unroll
    for (int n = 0; n < 2; ++n) {
      bg[n][0] = RD(sB[BUF], bRow + n * 1024 + kOff0);
      bg[n][1] = RD(sB[BUF], bRow + n * 1024 + kOff1);
    }
#pragma unroll
    for (int n = 0; n < 2; ++n) {   // bu: consumed ph2 -> overlaps this MFMA
      bu[n][0] = RD(sB[BUF], bRow + 2048 + n * 1024 + kOff0);
      bu[n][1] = RD(sB[BUF], bRow + 2048 + n * 1024 + kOff1);
    }
    __builtin_amdgcn_s_setprio(1);
#pragma unroll
    for (int m = 0; m < 4; ++m)
#pragma unroll
      for (int n = 0; n < 2; ++n)
#pragma unroll
        for (int ks = 0; ks < 2; ++ks)
          acc[m][n] = __builtin_amdgcn_mfma_f32_16x16x32_bf16(aLo[m][ks], bg[n][ks], acc[m][n], 0, 0, 0);
    __builtin_amdgcn_s_setprio(0);
    PHASE_BAR();

    // ---- ph2: stage A-hi(t+1); read aHi (for ph3) inside MFMA region ----
    if (stA) {
      async_copy16(aSrc[2] + kA, &sA[ALT][2 * 4096 + wid * 512]);
      async_copy16(aSrc[3] + kA, &sA[ALT][3 * 4096 + wid * 512]);
    }
    PHASE_BAR();
#pragma unroll
    for (int m = 0; m < 4; ++m) {
      aHi[m][0] = RD(sA[BUF], aRow + 4096 + m * 1024 + kOff0);
      aHi[m][1] = RD(sA[BUF], aRow + 4096 + m * 1024 + kOff1);
    }
    __builtin_amdgcn_s_setprio(1);
#pragma unroll
    for (int m = 0; m < 4; ++m)
#pragma unroll
      for (int n = 0; n < 2; ++n)
#pragma unroll
        for (int ks = 0; ks < 2; ++ks)
          acc[m][2 + n] = __builtin_amdgcn_mfma_f32_16x16x32_bf16(aLo[m][ks], bu[n][ks], acc[m][2 + n], 0, 0, 0);
    __builtin_amdgcn_s_setprio(0);
    PHASE_BAR();

    // ---- ph3: stage B-lo(t+2) into same-parity buffer; MFMA Qu-hi ----
    if (stB) {
      async_copy16(bSrc[0] + kB, &sB[BUF][0 * 4096 + wid * 512]);
      async_copy16(bSrc[1] + kB, &sB[BUF][1 * 4096 + wid * 512]);
    }
    PHASE_BAR();
    __builtin_amdgcn_s_setprio(1);
#pragma unroll
    for (int m = 0; m < 4; ++m)
#pragma unroll
      for (int n = 0; n < 2; ++n)
#pragma unroll
        for (int ks = 0; ks < 2; ++ks)
          acc[4 + m][2 + n] = __builtin_amdgcn_mfma_f32_16x16x32_bf16(aHi[m][ks], bu[n][ks], acc[4 + m][2 + n], 0, 0, 0);
    __builtin_amdgcn_s_setprio(0);
    PHASE_BAR();

    // ---- ph4: stage B-hi(t+2); MFMA Qg-hi; boundary counted vmcnt ----
    if (stB) {
      async_copy16(bSrc[2] + kB, &sB[BUF][2 * 4096 + wid * 512]);
      async_copy16(bSrc[3] + kB, &sB[BUF][3 * 4096 + wid * 512]);
    }
    __builtin_amdgcn_s_setprio(1);
#pragma unroll
    for (int m = 0; m < 4; ++m)
#pragma unroll
      for (int n = 0; n < 2; ++n)
#pragma unroll
        for (int ks = 0; ks < 2; ++ks)
          acc[4 + m][n] = __builtin_amdgcn_mfma_f32_16x16x32_bf16(aHi[m][ks], bg[n][ks], acc[4 + m][n], 0, 0, 0);
    __builtin_amdgcn_s_setprio(0);
    if (stB) { WAIT_VM(4); } else { WAIT_VM(0); }
    PHASE_BAR();
  };

  for (int t = 0; t < NK; t += 2) {
    iter(0, 1, t);
    iter(1, 0, t + 1);
  }

  // epilogue: h = silu(g)*u
#pragma unroll
  for (int mm = 0; mm < 8; ++mm) {
#pragma unroll
    for (int np = 0; np < 2; ++np) {
      int col = jbase + wc * 32 + np * 16 + l15;
#pragma unroll
      for (int j = 0; j < 4; ++j) {
        int rl = wr * 128 + mm * 16 + lhi * 4 + j;
        int i = rowbase + rl;
        if (i < ne) {
          float g = acc[mm][np][j], u = acc[mm][np + 2][j];
          float hv = (g / (1.f + __expf(-g))) * u;
          hbuf[(size_t)(hb + i) * I_DIM + col] = __float2bfloat16(hv);
        }
      }
    }
  }
}

// ============================================================================
// GEMM2: y[slot] = coef * (h[slot] @ W2^T), compact bf16 ybuf. Same schedule.
// ============================================================================
__global__ __launch_bounds__(512, 2) void gemm2_kernel(
    const __hip_bfloat16* __restrict__ hbuf, const __hip_bfloat16* __restrict__ wb2,
    const int* __restrict__ cnt, const int* __restrict__ base,
    const float* __restrict__ wgt, __hip_bfloat16* __restrict__ ybuf)
{
  // 640 blocks = 8 XCDs x 80 (10 row-blocks x 8 col-blocks per expert)
  int lin = blockIdx.x;
  int swz = (lin & 7) * 80 + (lin >> 3);
  int e = swz / 80; int rem = swz - e * 80;
  int by = rem >> 3; int bx = rem & 7;
  const int ne = cnt[e];
  const int rowbase = by * 256;
  if (rowbase >= ne) return;
  const int nbase = bx * 256;
  const int hb = base[e];

  __shared__ short sA[2][256 * 64];
  __shared__ short sB[2][256 * 64];
  __shared__ float sW[256];

  const int tid = threadIdx.x, wid = tid >> 6, lane = tid & 63;
  const int wr = wid >> 2, wc = wid & 3;
  const int l15 = lane & 15, lhi = lane >> 4;
  const float* wgt_e = wgt + e * T_TOK;
  const char* hs = (const char*)hbuf;
  const char* w2s = (const char*)wb2 + (size_t)e * H_DIM * I_DIM * 2;

  if (tid < 256) {
    int i = rowbase + tid;
    sW[tid] = (i < ne) ? wgt_e[i] : 0.f;
  }

  const int swz45 = (lhi ^ (l15 & 3)) << 3;
  const int b6s   = ((l15 >> 2) & 1) << 5;
  const int kOff0 = swz45 + (0 ^ b6s);
  const int kOff1 = swz45 + (32 ^ b6s);
  const int aRow  = (wr * 128 + l15) * 64;
  const int bRow  = (wc * 64 + l15) * 64;

  const int cb = ((lane & 7) ^ (lane >> 3)) << 4;
  const char* aSrc[4]; const char* bSrc[4];
#pragma unroll
  for (int q = 0; q < 4; ++q) {
    int r = q * 64 + wid * 8 + (lane >> 3);
    int i = rowbase + r; if (i > ne - 1) i = ne - 1;
    aSrc[q] = hs + (size_t)(hb + i) * (I_DIM * 2) + cb;
    bSrc[q] = w2s + (size_t)(nbase + r) * (I_DIM * 2) + cb;
  }

  const int NK = I_DIM / 64;  // 22 (even)

#pragma unroll
  for (int q = 0; q < 4; ++q) async_copy16(bSrc[q], &sB[0][q * 4096 + wid * 512]);
#pragma unroll
  for (int q = 0; q < 4; ++q) async_copy16(aSrc[q], &sA[0][q * 4096 + wid * 512]);
#pragma unroll
  for (int q = 0; q < 4; ++q) async_copy16(bSrc[q] + 128, &sB[1][q * 4096 + wid * 512]);
#pragma unroll
  for (int q = 0; q < 4; ++q) async_copy16(aSrc[q] + 128, &sA[1][q * 4096 + wid * 512]);
  WAIT_VM(8);
  PHASE_BAR();

  f32x4 acc[8][4];
#pragma unroll
  for (int m = 0; m < 8; ++m)
#pragma unroll
    for (int n = 0; n < 4; ++n) acc[m][n] = (f32x4){0, 0, 0, 0};

  auto iter = [&](const int BUF, const int ALT, const int t) {
    const bool stA = (t >= 1) && (t + 1 < NK);
    const bool stB = (t + 2 < NK);
    const size_t kA = (size_t)(t + 1) * 128;
    const size_t kB = (size_t)(t + 2) * 128;
    bf16x8 aLo[4][2], aHi[4][2], b0[2][2], b1[2][2];

    // ph1
    if (stA) {
      async_copy16(aSrc[0] + kA, &sA[ALT][0 * 4096 + wid * 512]);
      async_copy16(aSrc[1] + kA, &sA[ALT][1 * 4096 + wid * 512]);
    }
    PHASE_BAR();
#pragma unroll
    for (int m = 0; m < 4; ++m) {
      aLo[m][0] = RD(sA[BUF], aRow + m * 1024 + kOff0);
      aLo[m][1] = RD(sA[BUF], aRow + m * 1024 + kOff1);
    }
#pragma unroll
    for (int n = 0; n < 2; ++n) {
      b0[n][0] = RD(sB[BUF], bRow + n * 1024 + kOff0);
      b0[n][1] = RD(sB[BUF], bRow + n * 1024 + kOff1);
    }
#pragma unroll
    for (int n = 0; n < 2; ++n) {
      b1[n][0] = RD(sB[BUF], bRow + 2048 + n * 1024 + kOff0);
      b1[n][1] = RD(sB[BUF], bRow + 2048 + n * 1024 + kOff1);
    }
    __builtin_amdgcn_s_setprio(1);
#pragma unroll
    for (int m = 0; m < 4; ++m)
#pragma unroll
      for (int n = 0; n < 2; ++n)
#pragma unroll
        for (int ks = 0; ks < 2; ++ks)
          acc[m][n] = __builtin_amdgcn_mfma_f32_16x16x32_bf16(aLo[m][ks], b0[n][ks], acc[m][n], 0, 0, 0);
    __builtin_amdgcn_s_setprio(0);
    PHASE_BAR();

    // ph2
    if (stA) {
      async_copy16(aSrc[2] + kA, &sA[ALT][2 * 4096 + wid * 512]);
      async_copy16(aSrc[3] + kA, &sA[ALT][3 * 4096 + wid * 512]);
    }
    PHASE_BAR();
#pragma unroll
    for (int m = 0; m < 4; ++m) {
      aHi[m][0] = RD(sA[BUF], aRow + 4096 + m * 1024 + kOff0);
      aHi[m][1] = RD(sA[BUF], aRow + 4096 + m * 1024 + kOff1);
    }
    __builtin_amdgcn_s_setprio(1);
#pragma unroll
    for (int m = 0; m < 4; ++m)
#pragma unroll
      for (int n = 0; n < 2; ++n)
#pragma unroll
        for (int ks = 0; ks < 2; ++ks)
          acc[m][2 + n] = __builtin_amdgcn_mfma_f32_16x16x32_bf16(aLo[m][ks], b1[n][ks], acc[m][2 + n], 0, 0, 0);
    __builtin_amdgcn_s_setprio(0);
    PHASE_BAR();

    // ph3
    if (stB) {
      async_copy16(bSrc[0] + kB, &sB[BUF][0 * 4096 + wid * 512]);
      async_copy16(bSrc[1] + kB, &sB[BUF][1 * 4096 + wid * 512]);
    }
    PHASE_BAR();
    __builtin_amdgcn_s_setprio(1);
#pragma unroll
    for (int m = 0; m < 4; ++m)
#pragma unroll
      for (int n = 0; n < 2; ++n)
#pragma unroll
        for (int ks = 0; ks < 2; ++ks)
          acc[4 + m][2 + n] = __builtin_amdgcn_mfma_f32_16x16x32_bf16(aHi[m][ks], b1[n][ks], acc[4 + m][2 + n], 0, 0, 0);
    __builtin_amdgcn_s_setprio(0);
    PHASE_BAR();

    // ph4
    if (stB) {
      async_copy16(bSrc[2] + kB, &sB[BUF][2 * 4096 + wid * 512]);
      async_copy16(bSrc[3] + kB, &sB[BUF][3 * 4096 + wid * 512]);
    }
    __builtin_amdgcn_s_setprio(1);
#pragma unroll
    for (int m = 0; m < 4; ++m)
#pragma unroll
      for (int n = 0; n < 2; ++n)
#pragma unroll
        for (int ks = 0; ks < 2; ++ks)
          acc[4 + m][n] = __builtin_amdgcn_mfma_f32_16x16x32_bf16(aHi[m][ks], b0[n][ks], acc[4 + m][n], 0, 0, 0);
    __builtin_amdgcn_s_setprio(0);
    if (stB) { WAIT_VM(4); } else { WAIT_VM(0); }
    PHASE_BAR();
  };

  for (int t = 0; t < NK; t += 2) {
    iter(0, 1, t);
    iter(1, 0, t + 1);
  }

#pragma unroll
  for (int mm = 0; mm < 8; ++mm) {
#pragma unroll
    for (int nn = 0; nn < 4; ++nn) {
      int col = nbase + wc * 64 + nn * 16 + l15;
#pragma unroll
      for (int j = 0; j < 4; ++j) {
        int rl = wr * 128 + mm * 16 + lhi * 4 + j;
        if (rowbase + rl < ne) {
          float y = acc[mm][nn][j] * sW[rl];
          ybuf[(size_t)(hb + rowbase + rl) * H_DIM + col] = __float2bfloat16(y);
        }
      }
    }
  }
}

// ---------------- combine: out[t] = y[slot1(t)] + y[slot2(t)] ----------------
__global__ __launch_bounds__(256) void combine_kernel(
    const __hip_bfloat16* __restrict__ ybuf, const int* __restrict__ base,
    const int* __restrict__ invE, const int* __restrict__ invP,
    float* __restrict__ out)
{
  int t = blockIdx.x;
  int s1 = base[invE[2 * t]] + invP[2 * t];
  int s2 = base[invE[2 * t + 1]] + invP[2 * t + 1];
  const ushort* y1 = (const ushort*)ybuf + (size_t)s1 * H_DIM;
  const ushort* y2 = (const ushort*)ybuf + (size_t)s2 * H_DIM;
  float* o = out + (size_t)t * H_DIM;
#pragma unroll
  for (int c0 = 0; c0 < H_DIM; c0 += 256 * 4) {
    int c = c0 + threadIdx.x * 4;
    ushort4 a = *(const ushort4*)(y1 + c);
    ushort4 b = *(const ushort4*)(y2 + c);
    float4 r;
    r.x = bfu2f(a.x) + bfu2f(b.x);
    r.y = bfu2f(a.y) + bfu2f(b.y);
    r.z = bfu2f(a.z) + bfu2f(b.z);
    r.w = bfu2f(a.w) + bfu2f(b.w);
    *(float4*)(o + c) = r;
  }
}

// ---------------- launch ----------------
extern "C" void kernel_launch(void* const* d_in, const int* in_sizes, int n_in,
                              void* d_out, int out_size, void* d_ws, size_t ws_size,
                              hipStream_t stream) {
  const float* x  = (const float*)d_in[0];
  const float* gw = (const float*)d_in[1];
  const float* w1 = (const float*)d_in[2];
  const float* w2 = (const float*)d_in[3];
  float* out = (float*)d_out;

  char* ws = (char*)d_ws;
  size_t o = 0;
  __hip_bfloat16* xb   = (__hip_bfloat16*)(ws + o); o += (size_t)T_TOK * H_DIM * 2;         // 33.5MB
  __hip_bfloat16* wb1  = (__hip_bfloat16*)(ws + o); o += (size_t)E_NUM * GU2 * H_DIM * 2;   // 92.3MB
  __hip_bfloat16* wb2  = (__hip_bfloat16*)(ws + o); o += (size_t)E_NUM * H_DIM * I_DIM * 2; // 46.1MB
  __hip_bfloat16* hbuf = (__hip_bfloat16*)(ws + o); o += (size_t)2 * T_TOK * I_DIM * 2;     // 46.1MB
  int*   idx  = (int*)(ws + o);   o += (size_t)E_NUM * T_TOK * 4;
  float* wgt  = (float*)(ws + o); o += (size_t)E_NUM * T_TOK * 4;
  int*   invE = (int*)(ws + o);   o += (size_t)2 * T_TOK * 4;
  int*   invP = (int*)(ws + o);   o += (size_t)2 * T_TOK * 4;
  int*   cnt  = (int*)(ws + o);   o += 64;
  int*   base = (int*)(ws + o);   o += 64;
  // ybuf (67.1MB bf16) aliases xb+wb1 (125.8MB): both dead once gemm1 completes.
  __hip_bfloat16* ybuf = (__hip_bfloat16*)ws;

  hipMemsetAsync(cnt, 0, 128, stream);  // cnt + base

  cvt_kernel<<<4096, 256, 0, stream>>>((const float4*)w1, (ushort4*)wb1, (E_NUM * GU2 * H_DIM) / 4);
  cvt_kernel<<<4096, 256, 0, stream>>>((const float4*)w2, (ushort4*)wb2, (E_NUM * H_DIM * I_DIM) / 4);

  gating_kernel<<<T_TOK / 4, 256, 0, stream>>>(x, gw, cnt, idx, wgt, invE, invP, xb);
  prefix_kernel<<<1, 64, 0, stream>>>(cnt, base);

  gemm1_kernel<<<dim3(880), 512, 0, stream>>>(xb, wb1, cnt, base, idx, hbuf);
  gemm2_kernel<<<dim3(640), 512, 0, stream>>>(hbuf, wb2, cnt, base, wgt, ybuf);

  combine_kernel<<<T_TOK, 256, 0, stream>>>(ybuf, base, invE, invP, out);
}

// Round 10
// 565.511 us; speedup vs baseline: 1.6726x; 1.6726x over previous
//
#include <hip/hip_runtime.h>
#include <hip/hip_bf16.h>
#include <stdint.h>

#define T_TOK 8192
#define H_DIM 2048
#define I_DIM 1408
#define E_NUM 8
#define GU2   2816   // 2*I

typedef __attribute__((ext_vector_type(8))) short bf16x8;
typedef __attribute__((ext_vector_type(4))) float f32x4;

__device__ __forceinline__ void async_copy16(const void* g, void* lds) {
  __builtin_amdgcn_global_load_lds(
      (const __attribute__((address_space(1))) uint32_t*)g,
      (__attribute__((address_space(3))) uint32_t*)lds, 16, 0, 0);
}

// Swizzled LDS read (compiler-visible): tile row stride 128B,
// byte ^= (row&7)<<4 — proven conflict-free (r2-r5: SQ_LDS_BANK_CONFLICT=0).
__device__ __forceinline__ bf16x8 lds_read_swz(const short* tile, int row, int kcol) {
  int byte = (row << 7) + (kcol << 1);
  byte ^= (row & 7) << 4;
  return *(const bf16x8*)((const char*)tile + byte);
}

__device__ __forceinline__ float bfu2f(unsigned short u) {
  union { unsigned int i; float f; } v; v.i = ((unsigned int)u) << 16; return v.f;
}

__device__ __forceinline__ ushort4 cvt4(float4 v) {
  ushort4 o;
  __hip_bfloat16 b;
  b = __float2bfloat16(v.x); o.x = *reinterpret_cast<unsigned short*>(&b);
  b = __float2bfloat16(v.y); o.y = *reinterpret_cast<unsigned short*>(&b);
  b = __float2bfloat16(v.z); o.z = *reinterpret_cast<unsigned short*>(&b);
  b = __float2bfloat16(v.w); o.w = *reinterpret_cast<unsigned short*>(&b);
  return o;
}

// ============================================================================
// prep: one launch = cvt(w1) [blocks 0..4095] + cvt(w2) [4096..6143]
//       + gating/top2/xb [6144..8191]. Independent work, overlapped.
// ============================================================================
__global__ __launch_bounds__(256) void prep_kernel(
    const float* __restrict__ x, const float* __restrict__ gw,
    const float4* __restrict__ w1, ushort4* __restrict__ wb1,
    const float4* __restrict__ w2, ushort4* __restrict__ wb2,
    int* __restrict__ cnt, int* __restrict__ idx, float* __restrict__ wgt,
    int* __restrict__ invE, int* __restrict__ invP,
    __hip_bfloat16* __restrict__ xb)
{
  int b = blockIdx.x;
  if (b < 4096) {
    const int n4 = (E_NUM * GU2 * H_DIM) / 4;
    int i = b * 256 + threadIdx.x;
    const int stride = 4096 * 256;
    for (; i < n4; i += stride) wb1[i] = cvt4(w1[i]);
    return;
  }
  if (b < 6144) {
    const int n4 = (E_NUM * H_DIM * I_DIM) / 4;
    int i = (b - 4096) * 256 + threadIdx.x;
    const int stride = 2048 * 256;
    for (; i < n4; i += stride) wb2[i] = cvt4(w2[i]);
    return;
  }
  // ---- gating ----
  int wave = threadIdx.x >> 6, lane = threadIdx.x & 63;
  int t = (b - 6144) * 4 + wave;
  if (t >= T_TOK) return;
  const float4* xr = (const float4*)(x + (size_t)t * H_DIM);
  ushort4* xo = (ushort4*)((unsigned short*)xb + (size_t)t * H_DIM);
  float acc[E_NUM];
#pragma unroll
  for (int e = 0; e < E_NUM; ++e) acc[e] = 0.f;
#pragma unroll
  for (int i = 0; i < H_DIM / 256; ++i) {
    int c = i * 64 + lane;
    float4 xv = xr[c];
    xo[c] = cvt4(xv);
#pragma unroll
    for (int e = 0; e < E_NUM; ++e) {
      float4 g = ((const float4*)(gw + (size_t)e * H_DIM))[c];
      acc[e] += xv.x * g.x + xv.y * g.y + xv.z * g.z + xv.w * g.w;
    }
  }
#pragma unroll
  for (int e = 0; e < E_NUM; ++e) {
    float s = acc[e];
#pragma unroll
    for (int o = 32; o > 0; o >>= 1) s += __shfl_xor(s, o);
    acc[e] = s;
  }
  if (lane == 0) {
    int i1 = 0; float v1 = acc[0];
#pragma unroll
    for (int e = 1; e < E_NUM; ++e) if (acc[e] > v1) { v1 = acc[e]; i1 = e; }
    int i2 = -1; float v2 = -3.4e38f;
#pragma unroll
    for (int e = 0; e < E_NUM; ++e) if (e != i1 && acc[e] > v2) { v2 = acc[e]; i2 = e; }
    float p2 = expf(v2 - v1);
    float winv = 1.f / (1.f + p2);
    float w1v = winv, w2v = p2 * winv;
    int p = atomicAdd(&cnt[i1], 1);
    idx[i1 * T_TOK + p] = t; wgt[i1 * T_TOK + p] = w1v;
    invE[2 * t] = i1; invP[2 * t] = p;
    p = atomicAdd(&cnt[i2], 1);
    idx[i2 * T_TOK + p] = t; wgt[i2 * T_TOK + p] = w2v;
    invE[2 * t + 1] = i2; invP[2 * t + 1] = p;
  }
}

__global__ void prefix_kernel(const int* __restrict__ cnt, int* __restrict__ base) {
  if (threadIdx.x == 0 && blockIdx.x == 0) {
    int s = 0;
#pragma unroll
    for (int e = 0; e < E_NUM; ++e) { base[e] = s; s += cnt[e]; }
  }
}

// ============================================================================
// GEMM1 (m97 structure): 128 slot-rows x 64 h-cols (g and u both computed).
// 256 threads / 4 waves (2x2), single 32 KiB LDS buffer, 2-barrier K-loop,
// ~3 blocks/CU — cross-block TLP hides the staging drain (m114/m97: 912 TF).
// LDS DMA layout: chunk q + wave wid covers rows q*32+wid*8..+8 ->
// byte base q*4096 + wid*1024 (wave-uniform; HW adds lane*16).
// ============================================================================
__global__ __launch_bounds__(256, 3) void gemm1_kernel(
    const __hip_bfloat16* __restrict__ xb, const __hip_bfloat16* __restrict__ wb1,
    const int* __restrict__ cnt, const int* __restrict__ base, const int* __restrict__ idx,
    __hip_bfloat16* __restrict__ hbuf)
{
  // 3520 blocks = 8 XCDs x 440 (20 row-blocks x 22 col-blocks per expert)
  int lin = blockIdx.x;
  int swz = (lin & 7) * 440 + (lin >> 3);
  int e = swz / 440; int rem = swz - e * 440;
  int by = rem / 22; int bx = rem - by * 22;
  const int ne = cnt[e];
  const int rowbase = by * 128;
  if (rowbase >= ne) return;
  const int jbase = bx * 64;
  const int hb = base[e];

  __shared__ short sA[128 * 64];   // 16 KiB
  __shared__ short sB[128 * 64];   // 16 KiB: rows 0-63 = gate, 64-127 = up

  const int tid = threadIdx.x, wid = tid >> 6, lane = tid & 63;
  const int wr = wid >> 1, wc = wid & 1;
  const int l15 = lane & 15, lhi = lane >> 4;
  const int* idx_e = idx + e * T_TOK;
  const char* xs = (const char*)xb;
  const char* w1s = (const char*)wb1 + (size_t)e * GU2 * H_DIM * 2;

  // staging: 4 chunks/thread each for A and B; source row = q*32 + tid>>3,
  // source col pre-swizzled so linear DMA dest + swizzled read match.
  const int cb = (((tid & 7) ^ ((tid >> 3) & 7)) << 4);
  const char* aSrc[4]; const char* bSrc[4];
#pragma unroll
  for (int q = 0; q < 4; ++q) {
    int r = q * 32 + (tid >> 3);
    int i = rowbase + r; if (i > ne - 1) i = ne - 1;
    aSrc[q] = xs + (size_t)idx_e[i] * (H_DIM * 2) + cb;
    int wrow = (r < 64) ? (jbase + r) : (I_DIM + jbase + (r - 64));
    bSrc[q] = w1s + (size_t)wrow * (H_DIM * 2) + cb;
  }

  f32x4 accg[4][2], accu[4][2];
#pragma unroll
  for (int m = 0; m < 4; ++m)
#pragma unroll
    for (int n = 0; n < 2; ++n) { accg[m][n] = (f32x4){0,0,0,0}; accu[m][n] = (f32x4){0,0,0,0}; }

  const int NK = H_DIM / 64;  // 32

  for (int kt = 0; kt < NK; ++kt) {
    const size_t koff = (size_t)kt * 128;
#pragma unroll
    for (int q = 0; q < 4; ++q) {
      async_copy16(aSrc[q] + koff, (char*)sA + q * 4096 + wid * 1024);
      async_copy16(bSrc[q] + koff, (char*)sB + q * 4096 + wid * 1024);
    }
    __syncthreads();

    bf16x8 a[4][2], bg[2][2], bu[2][2];
#pragma unroll
    for (int m = 0; m < 4; ++m)
#pragma unroll
      for (int ks = 0; ks < 2; ++ks)
        a[m][ks] = lds_read_swz(sA, wr * 64 + m * 16 + l15, ks * 32 + (lhi << 3));
#pragma unroll
    for (int n = 0; n < 2; ++n)
#pragma unroll
      for (int ks = 0; ks < 2; ++ks) {
        bg[n][ks] = lds_read_swz(sB, wc * 32 + n * 16 + l15, ks * 32 + (lhi << 3));
        bu[n][ks] = lds_read_swz(sB, 64 + wc * 32 + n * 16 + l15, ks * 32 + (lhi << 3));
      }
    __builtin_amdgcn_s_setprio(1);
#pragma unroll
    for (int m = 0; m < 4; ++m)
#pragma unroll
      for (int n = 0; n < 2; ++n)
#pragma unroll
        for (int ks = 0; ks < 2; ++ks) {
          accg[m][n] = __builtin_amdgcn_mfma_f32_16x16x32_bf16(a[m][ks], bg[n][ks], accg[m][n], 0, 0, 0);
          accu[m][n] = __builtin_amdgcn_mfma_f32_16x16x32_bf16(a[m][ks], bu[n][ks], accu[m][n], 0, 0, 0);
        }
    __builtin_amdgcn_s_setprio(0);
    __syncthreads();
  }

  // epilogue: h = silu(g)*u
#pragma unroll
  for (int m = 0; m < 4; ++m) {
#pragma unroll
    for (int n = 0; n < 2; ++n) {
      int col = jbase + wc * 32 + n * 16 + l15;
#pragma unroll
      for (int j = 0; j < 4; ++j) {
        int rl = wr * 64 + m * 16 + lhi * 4 + j;
        int i = rowbase + rl;
        if (i < ne) {
          float g = accg[m][n][j], u = accu[m][n][j];
          float hv = (g / (1.f + __expf(-g))) * u;
          hbuf[(size_t)(hb + i) * I_DIM + col] = __float2bfloat16(hv);
        }
      }
    }
  }
}

// ============================================================================
// GEMM2 (m97 structure): 128 slot-rows x 128 out-cols, same skeleton.
// y[slot] = coef * (h[slot] @ W2^T), compact bf16 ybuf.
// ============================================================================
__global__ __launch_bounds__(256, 3) void gemm2_kernel(
    const __hip_bfloat16* __restrict__ hbuf, const __hip_bfloat16* __restrict__ wb2,
    const int* __restrict__ cnt, const int* __restrict__ base,
    const float* __restrict__ wgt, __hip_bfloat16* __restrict__ ybuf)
{
  // 2560 blocks = 8 XCDs x 320 (20 row-blocks x 16 col-blocks per expert)
  int lin = blockIdx.x;
  int swz = (lin & 7) * 320 + (lin >> 3);
  int e = swz / 320; int rem = swz - e * 320;
  int by = rem >> 4; int bx = rem & 15;
  const int ne = cnt[e];
  const int rowbase = by * 128;
  if (rowbase >= ne) return;
  const int nbase = bx * 128;
  const int hb = base[e];

  __shared__ short sA[128 * 64];
  __shared__ short sB[128 * 64];
  __shared__ float sW[128];

  const int tid = threadIdx.x, wid = tid >> 6, lane = tid & 63;
  const int wr = wid >> 1, wc = wid & 1;
  const int l15 = lane & 15, lhi = lane >> 4;
  const float* wgt_e = wgt + e * T_TOK;
  const char* hs = (const char*)hbuf;
  const char* w2s = (const char*)wb2 + (size_t)e * H_DIM * I_DIM * 2;

  if (tid < 128) {
    int i = rowbase + tid;
    sW[tid] = (i < ne) ? wgt_e[i] : 0.f;
  }

  const int cb = (((tid & 7) ^ ((tid >> 3) & 7)) << 4);
  const char* aSrc[4]; const char* bSrc[4];
#pragma unroll
  for (int q = 0; q < 4; ++q) {
    int r = q * 32 + (tid >> 3);
    int i = rowbase + r; if (i > ne - 1) i = ne - 1;
    aSrc[q] = hs + (size_t)(hb + i) * (I_DIM * 2) + cb;
    bSrc[q] = w2s + (size_t)(nbase + r) * (I_DIM * 2) + cb;
  }

  f32x4 acc[4][4];
#pragma unroll
  for (int m = 0; m < 4; ++m)
#pragma unroll
    for (int n = 0; n < 4; ++n) acc[m][n] = (f32x4){0, 0, 0, 0};

  const int NK = I_DIM / 64;  // 22

  for (int kt = 0; kt < NK; ++kt) {
    const size_t koff = (size_t)kt * 128;
#pragma unroll
    for (int q = 0; q < 4; ++q) {
      async_copy16(aSrc[q] + koff, (char*)sA + q * 4096 + wid * 1024);
      async_copy16(bSrc[q] + koff, (char*)sB + q * 4096 + wid * 1024);
    }
    __syncthreads();

    bf16x8 a[4][2], b[4][2];
#pragma unroll
    for (int m = 0; m < 4; ++m)
#pragma unroll
      for (int ks = 0; ks < 2; ++ks)
        a[m][ks] = lds_read_swz(sA, wr * 64 + m * 16 + l15, ks * 32 + (lhi << 3));
#pragma unroll
    for (int n = 0; n < 4; ++n)
#pragma unroll
      for (int ks = 0; ks < 2; ++ks)
        b[n][ks] = lds_read_swz(sB, wc * 64 + n * 16 + l15, ks * 32 + (lhi << 3));
    __builtin_amdgcn_s_setprio(1);
#pragma unroll
    for (int m = 0; m < 4; ++m)
#pragma unroll
      for (int n = 0; n < 4; ++n)
#pragma unroll
        for (int ks = 0; ks < 2; ++ks)
          acc[m][n] = __builtin_amdgcn_mfma_f32_16x16x32_bf16(a[m][ks], b[n][ks], acc[m][n], 0, 0, 0);
    __builtin_amdgcn_s_setprio(0);
    __syncthreads();
  }

#pragma unroll
  for (int m = 0; m < 4; ++m)
#pragma unroll
    for (int n = 0; n < 4; ++n) {
      int col = nbase + wc * 64 + n * 16 + l15;
#pragma unroll
      for (int j = 0; j < 4; ++j) {
        int rl = wr * 64 + m * 16 + lhi * 4 + j;
        if (rowbase + rl < ne) {
          float y = acc[m][n][j] * sW[rl];
          ybuf[(size_t)(hb + rowbase + rl) * H_DIM + col] = __float2bfloat16(y);
        }
      }
    }
}

// ---------------- combine: out[t] = y[slot1(t)] + y[slot2(t)] ----------------
__global__ __launch_bounds__(256) void combine_kernel(
    const __hip_bfloat16* __restrict__ ybuf, const int* __restrict__ base,
    const int* __restrict__ invE, const int* __restrict__ invP,
    float* __restrict__ out)
{
  int t = blockIdx.x;
  int s1 = base[invE[2 * t]] + invP[2 * t];
  int s2 = base[invE[2 * t + 1]] + invP[2 * t + 1];
  const ushort* y1 = (const ushort*)ybuf + (size_t)s1 * H_DIM;
  const ushort* y2 = (const ushort*)ybuf + (size_t)s2 * H_DIM;
  float* o = out + (size_t)t * H_DIM;
#pragma unroll
  for (int c0 = 0; c0 < H_DIM; c0 += 256 * 4) {
    int c = c0 + threadIdx.x * 4;
    ushort4 a = *(const ushort4*)(y1 + c);
    ushort4 b = *(const ushort4*)(y2 + c);
    float4 r;
    r.x = bfu2f(a.x) + bfu2f(b.x);
    r.y = bfu2f(a.y) + bfu2f(b.y);
    r.z = bfu2f(a.z) + bfu2f(b.z);
    r.w = bfu2f(a.w) + bfu2f(b.w);
    *(float4*)(o + c) = r;
  }
}

// ---------------- launch ----------------
extern "C" void kernel_launch(void* const* d_in, const int* in_sizes, int n_in,
                              void* d_out, int out_size, void* d_ws, size_t ws_size,
                              hipStream_t stream) {
  const float* x  = (const float*)d_in[0];
  const float* gw = (const float*)d_in[1];
  const float* w1 = (const float*)d_in[2];
  const float* w2 = (const float*)d_in[3];
  float* out = (float*)d_out;

  char* ws = (char*)d_ws;
  size_t o = 0;
  __hip_bfloat16* xb   = (__hip_bfloat16*)(ws + o); o += (size_t)T_TOK * H_DIM * 2;         // 33.5MB
  __hip_bfloat16* wb1  = (__hip_bfloat16*)(ws + o); o += (size_t)E_NUM * GU2 * H_DIM * 2;   // 92.3MB
  __hip_bfloat16* wb2  = (__hip_bfloat16*)(ws + o); o += (size_t)E_NUM * H_DIM * I_DIM * 2; // 46.1MB
  __hip_bfloat16* hbuf = (__hip_bfloat16*)(ws + o); o += (size_t)2 * T_TOK * I_DIM * 2;     // 46.1MB
  int*   idx  = (int*)(ws + o);   o += (size_t)E_NUM * T_TOK * 4;
  float* wgt  = (float*)(ws + o); o += (size_t)E_NUM * T_TOK * 4;
  int*   invE = (int*)(ws + o);   o += (size_t)2 * T_TOK * 4;
  int*   invP = (int*)(ws + o);   o += (size_t)2 * T_TOK * 4;
  int*   cnt  = (int*)(ws + o);   o += 64;
  int*   base = (int*)(ws + o);   o += 64;
  // ybuf (67.1MB bf16) aliases xb+wb1 (125.8MB): both dead once gemm1 completes.
  __hip_bfloat16* ybuf = (__hip_bfloat16*)ws;

  hipMemsetAsync(cnt, 0, 128, stream);  // cnt + base

  prep_kernel<<<8192, 256, 0, stream>>>(x, gw, (const float4*)w1, (ushort4*)wb1,
                                        (const float4*)w2, (ushort4*)wb2,
                                        cnt, idx, wgt, invE, invP, xb);
  prefix_kernel<<<1, 64, 0, stream>>>(cnt, base);

  gemm1_kernel<<<dim3(3520), 256, 0, stream>>>(xb, wb1, cnt, base, idx, hbuf);
  gemm2_kernel<<<dim3(2560), 256, 0, stream>>>(hbuf, wb2, cnt, base, wgt, ybuf);

  combine_kernel<<<T_TOK, 256, 0, stream>>>(ybuf, base, invE, invP, out);
}